// Round 2
// baseline (2020.109 us; speedup 1.0000x reference)
//
#include <hip/hip_runtime.h>
#include <stdint.h>

#define NN 64
#define DEG 30   // Chebyshev degree for log on [aLo, aHi]

// acc(4x4 tile at rows r4.., cols c4..) += A * B
// A is exactly symmetric by construction: read A[k][r] so both operand
// streams are row-contiguous float4 LDS reads.
__device__ __forceinline__ void mm64(const float* __restrict__ A,
                                     const float* __restrict__ B,
                                     int r4, int c4, float* __restrict__ acc) {
#pragma unroll 8
    for (int k = 0; k < NN; ++k) {
        const float4 av = *(const float4*)(A + (k << 6) + r4);
        const float4 bv = *(const float4*)(B + (k << 6) + c4);
        acc[0]  = fmaf(av.x, bv.x, acc[0]);
        acc[1]  = fmaf(av.x, bv.y, acc[1]);
        acc[2]  = fmaf(av.x, bv.z, acc[2]);
        acc[3]  = fmaf(av.x, bv.w, acc[3]);
        acc[4]  = fmaf(av.y, bv.x, acc[4]);
        acc[5]  = fmaf(av.y, bv.y, acc[5]);
        acc[6]  = fmaf(av.y, bv.z, acc[6]);
        acc[7]  = fmaf(av.y, bv.w, acc[7]);
        acc[8]  = fmaf(av.z, bv.x, acc[8]);
        acc[9]  = fmaf(av.z, bv.y, acc[9]);
        acc[10] = fmaf(av.z, bv.z, acc[10]);
        acc[11] = fmaf(av.z, bv.w, acc[11]);
        acc[12] = fmaf(av.w, bv.x, acc[12]);
        acc[13] = fmaf(av.w, bv.y, acc[13]);
        acc[14] = fmaf(av.w, bv.z, acc[14]);
        acc[15] = fmaf(av.w, bv.w, acc[15]);
    }
}

__global__ __launch_bounds__(256, 3)
void spdlogexp(const float* __restrict__ fin,
               const float* __restrict__ win,
               float* __restrict__ outp) {
    __shared__ __align__(16) float S0[NN * NN];
    __shared__ __align__(16) float S1[NN * NN];
    __shared__ __align__(16) float S2[NN * NN];
    __shared__ float wsh[NN];
    __shared__ float cheb[DEG + 1];

    const int tid = threadIdx.x;
    const int blk = blockIdx.x;
    const int r4 = (tid >> 4) << 2;
    const int c4 = (tid & 15) << 2;

    // Spectrum of X = A*A^T + 0.1I guaranteed in [0.1, ~5.7]; margins both ways.
    const float aLo = 0.09f, aHi = 6.3f;
    const float mC = 0.5f * (aLo + aHi);
    const float rC = 0.5f * (aHi - aLo);
    const float invR = 1.0f / rC;

    // ---- load X (f32), build T = (X - mC*I)/rC into S0, coalesced float4 ----
    {
        const float4* src = (const float4*)(fin + (size_t)blk * (NN * NN));
#pragma unroll
        for (int c = 0; c < 4; ++c) {
            int v4 = c * 256 + tid;          // float4 index, lane-contiguous
            float4 v = src[v4];
            int e0 = v4 << 2;
            float vv[4] = {v.x, v.y, v.z, v.w};
#pragma unroll
            for (int q = 0; q < 4; ++q) {
                int e = e0 + q;
                int i = e >> 6, j = e & 63;
                S0[e] = (vv[q] - ((i == j) ? mC : 0.0f)) * invR;
            }
        }
    }
    if (tid < NN) wsh[tid] = win[(size_t)blk * NN + tid];
    if (tid == 0) {
        // log(mC + rC*t) = log(Cc) - 2 * sum_{k>=1} (u^k/k) T_k(t),
        // u = -m/r + sqrt((m/r)^2 - 1), Cc = -rC/(2u)
        float mr = mC / rC;
        float u = -mr + sqrtf(mr * mr - 1.0f);
        float Cc = -rC / (2.0f * u);
        cheb[0] = logf(Cc);
        float p = 1.0f;
        for (int k = 1; k <= DEG; ++k) { p *= u; cheb[k] = -2.0f * p / (float)k; }
    }

    float* Tm = S0;
    float* cur = S1;
    float* prev = S2;

    __syncthreads();

    // ---- Clenshaw init: cur = b_{N-1} = 2 c_N T + c_{N-1} I ; prev = b_N = c_N I
    {
        const float cN = cheb[DEG], cNm1 = cheb[DEG - 1];
#pragma unroll
        for (int q = 0; q < 16; ++q) {
            int e = tid * 16 + q;
            int i = e >> 6, j = e & 63;
            float d = (i == j) ? 1.0f : 0.0f;
            cur[e] = 2.0f * cN * Tm[e] + cNm1 * d;
            prev[e] = cN * d;
        }
    }
    __syncthreads();

    // ---- Clenshaw: b_k = 2 T b_{k+1} - b_{k+2} + c_k I,  k = N-2 .. 1
    for (int k = DEG - 2; k >= 1; --k) {
        float acc[16];
#pragma unroll
        for (int q = 0; q < 16; ++q) acc[q] = 0.0f;
        mm64(Tm, cur, r4, c4, acc);
        const float ck = cheb[k];
#pragma unroll
        for (int ii = 0; ii < 4; ++ii)
#pragma unroll
            for (int jj = 0; jj < 4; ++jj) {
                int i = r4 + ii, j = c4 + jj;
                int e = i * NN + j;
                prev[e] = 2.0f * acc[ii * 4 + jj] - prev[e] + ((i == j) ? ck : 0.0f);
            }
        __syncthreads();
        float* t2 = cur; cur = prev; prev = t2;
    }

    // ---- final: L = T b_1 - b_2 + c_0 I  -> prev
    {
        float acc[16];
#pragma unroll
        for (int q = 0; q < 16; ++q) acc[q] = 0.0f;
        mm64(Tm, cur, r4, c4, acc);
        const float c0v = cheb[0];
#pragma unroll
        for (int ii = 0; ii < 4; ++ii)
#pragma unroll
            for (int jj = 0; jj < 4; ++jj) {
                int i = r4 + ii, j = c4 + jj;
                int e = i * NN + j;
                prev[e] = acc[ii * 4 + jj] - prev[e] + ((i == j) ? c0v : 0.0f);
            }
    }
    __syncthreads();

    float* Abuf = prev;  // A = M/16
    float* M2b = cur;    // b1: dead
    float* M3b = Tm;     // T: dead

    // ---- A = (w_i * w_j * L_ij) / 16  (scaling-squaring s=4), in place ----
#pragma unroll
    for (int q = 0; q < 16; ++q) {
        int e = tid * 16 + q;
        int i = e >> 6, j = e & 63;
        Abuf[e] = wsh[i] * wsh[j] * 0.0625f * Abuf[e];
    }
    __syncthreads();

    // ---- M2 = A*A ----
    {
        float acc[16];
#pragma unroll
        for (int q = 0; q < 16; ++q) acc[q] = 0.0f;
        mm64(Abuf, Abuf, r4, c4, acc);
#pragma unroll
        for (int ii = 0; ii < 4; ++ii)
#pragma unroll
            for (int jj = 0; jj < 4; ++jj)
                M2b[(r4 + ii) * NN + (c4 + jj)] = acc[ii * 4 + jj];
    }
    __syncthreads();

    // ---- M3 = A*M2 ----
    {
        float acc[16];
#pragma unroll
        for (int q = 0; q < 16; ++q) acc[q] = 0.0f;
        mm64(Abuf, M2b, r4, c4, acc);
#pragma unroll
        for (int ii = 0; ii < 4; ++ii)
#pragma unroll
            for (int jj = 0; jj < 4; ++jj)
                M3b[(r4 + ii) * NN + (c4 + jj)] = acc[ii * 4 + jj];
    }
    __syncthreads();

    // ---- b0 = I + A + M2/2 (regs);  G = I/6 + A/24 + M2/120 + M3/720 (over A)
    float b0r[16];
#pragma unroll
    for (int ii = 0; ii < 4; ++ii)
#pragma unroll
        for (int jj = 0; jj < 4; ++jj) {
            int i = r4 + ii, j = c4 + jj;
            int e = i * NN + j;
            float d = (i == j) ? 1.0f : 0.0f;
            float a = Abuf[e], m2 = M2b[e], m3 = M3b[e];
            b0r[ii * 4 + jj] = d + a + 0.5f * m2;
            Abuf[e] = (1.0f / 6.0f) * d + (1.0f / 24.0f) * a +
                      (1.0f / 120.0f) * m2 + (1.0f / 720.0f) * m3;
        }
    __syncthreads();

    // ---- P = b0 + G*M3  -> M2b   (deg-6 Taylor of exp(A), Paterson-Stockmeyer)
    {
        float acc[16];
#pragma unroll
        for (int q = 0; q < 16; ++q) acc[q] = 0.0f;
        mm64(Abuf, M3b, r4, c4, acc);
#pragma unroll
        for (int ii = 0; ii < 4; ++ii)
#pragma unroll
            for (int jj = 0; jj < 4; ++jj)
                M2b[(r4 + ii) * NN + (c4 + jj)] = acc[ii * 4 + jj] + b0r[ii * 4 + jj];
    }
    __syncthreads();

    // ---- 4 squarings: exp(M) = P^16 ----
    float* s = M2b;
    float* d = Abuf;
    for (int it = 0; it < 4; ++it) {
        float acc[16];
#pragma unroll
        for (int q = 0; q < 16; ++q) acc[q] = 0.0f;
        mm64(s, s, r4, c4, acc);
#pragma unroll
        for (int ii = 0; ii < 4; ++ii)
#pragma unroll
            for (int jj = 0; jj < 4; ++jj)
                d[(r4 + ii) * NN + (c4 + jj)] = acc[ii * 4 + jj];
        __syncthreads();
        float* t2 = s; s = d; d = t2;
    }

    // ---- store f32, coalesced float4 ----
    {
        float4* dst = (float4*)(outp + (size_t)blk * (NN * NN));
#pragma unroll
        for (int c = 0; c < 4; ++c) {
            int v4 = c * 256 + tid;
            int e0 = v4 << 2;
            float4 v;
            v.x = s[e0]; v.y = s[e0 + 1]; v.z = s[e0 + 2]; v.w = s[e0 + 3];
            dst[v4] = v;
        }
    }
}

extern "C" void kernel_launch(void* const* d_in, const int* in_sizes, int n_in,
                              void* d_out, int out_size, void* d_ws, size_t ws_size,
                              hipStream_t stream) {
    const float* f = (const float*)d_in[0];
    const float* w = (const float*)d_in[1];
    float* o = (float*)d_out;
    int B = in_sizes[0] / (NN * NN);
    spdlogexp<<<dim3(B), dim3(256), 0, stream>>>(f, w, o);
}

// Round 3
// 735.433 us; speedup vs baseline: 2.7468x; 2.7468x over previous
//
#include <hip/hip_runtime.h>
#include <stdint.h>

#define NN 64
#define LDP 72            // padded row stride (bf16 elems) = 144 B: optimal bank spread
#define PL  (NN * LDP)    // plane size in shorts (4608)
#define DEG 30            // Chebyshev degree for log on [aLo, aHi]

typedef __attribute__((ext_vector_type(8))) short short8;   // 8 bf16 = 4 VGPRs
typedef __attribute__((ext_vector_type(4))) float f32x4;

#define MFMA(a, b, c) __builtin_amdgcn_mfma_f32_16x16x32_bf16((a), (b), (c), 0, 0, 0)

__device__ __forceinline__ float bf2f(uint32_t h) {
    union { uint32_t i; float f; } v; v.i = h << 16; return v.f;
}
__device__ __forceinline__ uint32_t f2bf(float x) {   // RNE
    union { uint32_t i; float f; } v; v.f = x;
    return (v.i + 0x7FFFu + ((v.i >> 16) & 1u)) >> 16;
}
__device__ __forceinline__ void split_bf(float x, uint32_t& h, uint32_t& l) {
    h = f2bf(x);
    l = f2bf(x - bf2f(h));
}

// Write 4 values (rows rbase..rbase+3, col c) TRANSPOSED: plane[c][rbase..rbase+3].
// Legal because every matrix here is symmetric. 4 consecutive bf16 = ds_write_b64.
__device__ __forceinline__ void wr4(short* plane, int c, int rbase,
                                    uint32_t h0, uint32_t h1, uint32_t h2, uint32_t h3) {
    uint2 p; p.x = h0 | (h1 << 16); p.y = h2 | (h3 << 16);
    *(uint2*)(plane + c * LDP + rbase) = p;
}
__device__ __forceinline__ void store_tile_hl(short* Ph, short* Pl, int c, int rbase,
                                              const float* v) {
    uint32_t h[4], l[4];
#pragma unroll
    for (int r = 0; r < 4; ++r) split_bf(v[r], h[r], l[r]);
    wr4(Ph, c, rbase, h[0], h[1], h[2], h[3]);
    wr4(Pl, c, rbase, l[0], l[1], l[2], l[3]);
}

// acc[t] += A*B rows [16wv,16wv+16) x cols [16t,16t+16), split-precision (3 MFMA/term).
__device__ __forceinline__ void mm_mfma(const short* Ah, const short* Al,
                                        const short* Bh, const short* Bl,
                                        int wv, int fr, int fq, f32x4* acc) {
#pragma unroll
    for (int kc = 0; kc < 2; ++kc) {
        const int ao = (16 * wv + fr) * LDP + kc * 32 + fq * 8;
        const short8 ah = *(const short8*)(Ah + ao);
        const short8 al = *(const short8*)(Al + ao);
        const int bo = fr * LDP + kc * 32 + fq * 8;
#pragma unroll
        for (int t = 0; t < 4; ++t) {
            const short8 bh = *(const short8*)(Bh + bo + t * (16 * LDP));
            const short8 bl = *(const short8*)(Bl + bo + t * (16 * LDP));
            acc[t] = MFMA(ah, bh, acc[t]);
            acc[t] = MFMA(ah, bl, acc[t]);
            acc[t] = MFMA(al, bh, acc[t]);
        }
    }
}

__global__ __launch_bounds__(256, 4)
void spdlogexp(const float* __restrict__ fin,
               const float* __restrict__ win,
               float* __restrict__ outp) {
    __shared__ __align__(16) short lds[4 * PL];   // 36864 B
    __shared__ float wsh[NN];
    __shared__ float cheb[DEG + 1];

    const int tid = threadIdx.x;
    const int blk = blockIdx.x;
    const int lane = tid & 63;
    const int wv = tid >> 6;          // wave id: owns C rows [16wv, 16wv+16)
    const int fr = lane & 15;         // A row / B col / C col (within 16)
    const int fq = lane >> 4;         // quad
    const int rbase = 16 * wv + 4 * fq;  // C-frag absolute row base (+reg 0..3)

    short* P0h = lds;
    short* P0l = lds + PL;
    short* P1h = lds + 2 * PL;
    short* P1l = lds + 3 * PL;

    const float aLo = 0.09f, aHi = 6.3f;
    const float mC = 0.5f * (aLo + aHi), rC = 0.5f * (aHi - aLo);
    const float invR = 1.0f / rC;

    // ---- Phase 0: load X (f32, coalesced), T = (X - mC I)/rC -> hi/lo bf16 in P0 ----
    {
        const float4* src = (const float4*)(fin + (size_t)blk * (NN * NN));
#pragma unroll
        for (int c = 0; c < 4; ++c) {
            int v4 = c * 256 + tid;
            float4 v = src[v4];
            int e0 = v4 << 2;
            int i = e0 >> 6, j = e0 & 63;     // row i, cols j..j+3
            float tv[4] = {v.x, v.y, v.z, v.w};
            uint32_t h[4], l[4];
#pragma unroll
            for (int q = 0; q < 4; ++q) {
                tv[q] = (tv[q] - ((j + q == i) ? mC : 0.0f)) * invR;
                split_bf(tv[q], h[q], l[q]);
            }
            wr4(P0h + 0, i, j, h[0], h[1], h[2], h[3]);   // row-major here: plane[i][j..j+3]
            wr4(P0l + 0, i, j, l[0], l[1], l[2], l[3]);
        }
    }
    if (tid < NN) wsh[tid] = win[(size_t)blk * NN + tid];
    if (tid <= DEG) {
        // log(mC + rC t) = log(Cc) - 2 sum_k (u^k/k) T_k(t);  u<0!
        float mr = mC / rC;
        float u = -(mr - sqrtf(mr * mr - 1.0f));
        float Cc = -rC / (2.0f * u);
        if (tid == 0) cheb[0] = logf(Cc);
        else {
            float pu = powf(-u, (float)tid);          // |u|^k
            if (tid & 1) pu = -pu;                    // restore sign
            cheb[tid] = -2.0f * pu / (float)tid;
        }
    }
    __syncthreads();

    // ---- Cache T A-fragments in registers (A operand of every Clenshaw matmul) ----
    short8 aTh[2], aTl[2];
#pragma unroll
    for (int kc = 0; kc < 2; ++kc) {
        int ao = (16 * wv + fr) * LDP + kc * 32 + fq * 8;
        aTh[kc] = *(const short8*)(P0h + ao);
        aTl[kc] = *(const short8*)(P0l + ao);
    }

    // ---- Clenshaw init at C-frag positions (T hi-only is plenty: |c_DEG| ~ 5e-5) ----
    float cur[16], prev[16];
#pragma unroll
    for (int t = 0; t < 4; ++t) {
        int col = 16 * t + fr;
#pragma unroll
        for (int r = 0; r < 4; ++r) {
            int row = rbase + r;
            float tv = bf2f((uint16_t)P0h[row * LDP + col]);
            float d = (row == col) ? 1.0f : 0.0f;
            cur[t * 4 + r] = 2.0f * cheb[DEG] * tv + cheb[DEG - 1] * d;   // b_{DEG-1}
            prev[t * 4 + r] = cheb[DEG] * d;                              // b_DEG
        }
    }
#pragma unroll
    for (int t = 0; t < 4; ++t)
        store_tile_hl(P1h, P1l, 16 * t + fr, rbase, &cur[t * 4]);
    __syncthreads();

    // ---- Clenshaw: b_k = 2 T b_{k+1} - b_{k+2} + c_k I  (k = DEG-2 .. 1), then
    //      L = T b_1 - b_2 + c_0 I  (k = 0, factor 1). b_{k+1} in LDS buf p; T cached.
    int p = 1;
    for (int k = DEG - 2; k >= 0; --k) {
        const short* Bh = p ? P1h : P0h;
        const short* Bl = p ? P1l : P0l;
        short* Wh = p ? P0h : P1h;
        short* Wl = p ? P0l : P1l;
        f32x4 acc[4];
#pragma unroll
        for (int t = 0; t < 4; ++t) acc[t] = (f32x4){0.f, 0.f, 0.f, 0.f};
#pragma unroll
        for (int kc = 0; kc < 2; ++kc) {
            const int bo = fr * LDP + kc * 32 + fq * 8;
#pragma unroll
            for (int t = 0; t < 4; ++t) {
                const short8 bh = *(const short8*)(Bh + bo + t * (16 * LDP));
                const short8 bl = *(const short8*)(Bl + bo + t * (16 * LDP));
                acc[t] = MFMA(aTh[kc], bh, acc[t]);
                acc[t] = MFMA(aTh[kc], bl, acc[t]);
                acc[t] = MFMA(aTl[kc], bh, acc[t]);
            }
        }
        const float ck = cheb[k];
        const float fac = (k == 0) ? 1.0f : 2.0f;
        float nv[16];
#pragma unroll
        for (int t = 0; t < 4; ++t)
#pragma unroll
            for (int r = 0; r < 4; ++r) {
                int row = rbase + r, col = 16 * t + fr;
                nv[t * 4 + r] = fac * acc[t][r] - prev[t * 4 + r] + ((row == col) ? ck : 0.0f);
            }
#pragma unroll
        for (int q = 0; q < 16; ++q) { prev[q] = cur[q]; cur[q] = nv[q]; }
        if (k > 0) {
#pragma unroll
            for (int t = 0; t < 4; ++t)
                store_tile_hl(Wh, Wl, 16 * t + fr, rbase, &cur[t * 4]);
            __syncthreads();
            p ^= 1;
        }
    }
    // cur[] = L fragments.

    // ---- A = (w_i w_j / 16) L  (scaling-squaring s=4) ----
    float aF[16];
#pragma unroll
    for (int t = 0; t < 4; ++t) {
        float wc = wsh[16 * t + fr];
#pragma unroll
        for (int r = 0; r < 4; ++r)
            aF[t * 4 + r] = wsh[rbase + r] * wc * 0.0625f * cur[t * 4 + r];
    }
    short* Xh = p ? P0h : P1h;   // free buffer (k==0 read the other one)
    short* Xl = p ? P0l : P1l;
    short* Yh = p ? P1h : P0h;
    short* Yl = p ? P1l : P0l;
#pragma unroll
    for (int t = 0; t < 4; ++t)
        store_tile_hl(Xh, Xl, 16 * t + fr, rbase, &aF[t * 4]);
    __syncthreads();

    // ---- M2 = A*A -> Y ----
    float m2F[16];
    {
        f32x4 acc[4];
#pragma unroll
        for (int t = 0; t < 4; ++t) acc[t] = (f32x4){0.f, 0.f, 0.f, 0.f};
        mm_mfma(Xh, Xl, Xh, Xl, wv, fr, fq, acc);
#pragma unroll
        for (int t = 0; t < 4; ++t)
#pragma unroll
            for (int r = 0; r < 4; ++r) m2F[t * 4 + r] = acc[t][r];
#pragma unroll
        for (int t = 0; t < 4; ++t)
            store_tile_hl(Yh, Yl, 16 * t + fr, rbase, &m2F[t * 4]);
    }
    __syncthreads();

    // ---- M3 = A*M2 (frags only), then G -> X, M3 -> Y ----
    float b0F[16];
    {
        f32x4 acc[4];
#pragma unroll
        for (int t = 0; t < 4; ++t) acc[t] = (f32x4){0.f, 0.f, 0.f, 0.f};
        mm_mfma(Xh, Xl, Yh, Yl, wv, fr, fq, acc);
        float gF[16];
#pragma unroll
        for (int t = 0; t < 4; ++t)
#pragma unroll
            for (int r = 0; r < 4; ++r) {
                int row = rbase + r, col = 16 * t + fr;
                float d = (row == col) ? 1.0f : 0.0f;
                float a = aF[t * 4 + r], m2 = m2F[t * 4 + r], m3 = acc[t][r];
                b0F[t * 4 + r] = d + a + 0.5f * m2;
                gF[t * 4 + r] = (1.0f / 6.0f) * d + (1.0f / 24.0f) * a +
                                (1.0f / 120.0f) * m2 + (1.0f / 720.0f) * m3;
            }
        __syncthreads();   // everyone done reading A(X), M2(Y)
#pragma unroll
        for (int t = 0; t < 4; ++t) {
            store_tile_hl(Xh, Xl, 16 * t + fr, rbase, &gF[t * 4]);
            float m3v[4] = {acc[t][0], acc[t][1], acc[t][2], acc[t][3]};
            store_tile_hl(Yh, Yl, 16 * t + fr, rbase, m3v);
        }
    }
    __syncthreads();

    // ---- P = b0 + G*M3 -> P0 (fixed home so squaring chain ends reading P1) ----
    {
        f32x4 acc[4];
#pragma unroll
        for (int t = 0; t < 4; ++t) acc[t] = (f32x4){0.f, 0.f, 0.f, 0.f};
        mm_mfma(Xh, Xl, Yh, Yl, wv, fr, fq, acc);
        float pF[16];
#pragma unroll
        for (int t = 0; t < 4; ++t)
#pragma unroll
            for (int r = 0; r < 4; ++r) pF[t * 4 + r] = acc[t][r] + b0F[t * 4 + r];
        __syncthreads();   // everyone done reading G/M3
#pragma unroll
        for (int t = 0; t < 4; ++t)
            store_tile_hl(P0h, P0l, 16 * t + fr, rbase, &pF[t * 4]);
    }
    __syncthreads();

    // ---- 4 squarings: exp(M) = P^16. P0 -> P1 -> P0 -> P1 -> (stage) ----
    const short *Sh = P0h, *Sl = P0l;
    short *Dh = P1h, *Dl = P1l;
    for (int it = 0; it < 4; ++it) {
        f32x4 acc[4];
#pragma unroll
        for (int t = 0; t < 4; ++t) acc[t] = (f32x4){0.f, 0.f, 0.f, 0.f};
        mm_mfma(Sh, Sl, Sh, Sl, wv, fr, fq, acc);
        if (it < 3) {
            float sv[16];
#pragma unroll
            for (int t = 0; t < 4; ++t)
#pragma unroll
                for (int r = 0; r < 4; ++r) sv[t * 4 + r] = acc[t][r];
#pragma unroll
            for (int t = 0; t < 4; ++t)
                store_tile_hl(Dh, Dl, 16 * t + fr, rbase, &sv[t * 4]);
            __syncthreads();
            const short* th = Sh; const short* tl = Sl;
            Sh = Dh; Sl = Dl; Dh = (short*)th; Dl = (short*)tl;
        } else {
            // stage transposed f32 (stride 68 breaks bank conflicts) over P0 region;
            // final mm read from P1 -- no overlap.
            float* stg = (float*)lds;
#pragma unroll
            for (int t = 0; t < 4; ++t) {
                f32x4 v;
#pragma unroll
                for (int r = 0; r < 4; ++r) v[r] = acc[t][r];
                *(f32x4*)(stg + (16 * t + fr) * 68 + rbase) = v;
            }
        }
    }
    __syncthreads();

    // ---- coalesced float4 store ----
    {
        const float* stg = (const float*)lds;
        float4* dst = (float4*)(outp + (size_t)blk * (NN * NN));
#pragma unroll
        for (int c = 0; c < 4; ++c) {
            int v4 = c * 256 + tid;
            int e0 = v4 << 2, i = e0 >> 6, j = e0 & 63;
            float4 v = *(const float4*)(stg + i * 68 + j);
            dst[v4] = v;
        }
    }
}

extern "C" void kernel_launch(void* const* d_in, const int* in_sizes, int n_in,
                              void* d_out, int out_size, void* d_ws, size_t ws_size,
                              hipStream_t stream) {
    const float* f = (const float*)d_in[0];
    const float* w = (const float*)d_in[1];
    float* o = (float*)d_out;
    int B = in_sizes[0] / (NN * NN);
    spdlogexp<<<dim3(B), dim3(256), 0, stream>>>(f, w, o);
}